// Round 1
// baseline (1131.950 us; speedup 1.0000x reference)
//
#include <hip/hip_runtime.h>
#include <hip/hip_bf16.h>

#define NN 100000
#define NE 1600000
#define HID 64
#define ALPHA 0.1f
#define COEF 0.3f   // (1-ALPHA)/K

// ---------------- CSR build ----------------

__global__ void count_kernel(const int* __restrict__ dst, int* __restrict__ cnt) {
    int e = blockIdx.x * blockDim.x + threadIdx.x;
    if (e < NE) atomicAdd(&cnt[dst[e]], 1);
}

// single block, 1024 threads: exclusive scan of cnt -> rowptr, copy to cursor,
// and dinv[i] = rsqrt(in_deg + 1)
__global__ void scan_kernel(const int* __restrict__ cnt, int* __restrict__ rowptr,
                            int* __restrict__ cursor, float* __restrict__ dinv) {
    __shared__ int sums[1024];
    const int t = threadIdx.x;
    const int chunk = (NN + 1023) >> 10;           // 98
    const int start = t * chunk;
    const int end   = min(start + chunk, NN);
    int s = 0;
    for (int i = start; i < end; ++i) s += cnt[i];
    sums[t] = s;
    __syncthreads();
    for (int off = 1; off < 1024; off <<= 1) {
        int v = (t >= off) ? sums[t - off] : 0;
        __syncthreads();
        if (t >= off) sums[t] += v;
        __syncthreads();
    }
    int run = (t == 0) ? 0 : sums[t - 1];
    for (int i = start; i < end; ++i) {
        rowptr[i] = run;
        cursor[i] = run;
        int c = cnt[i];
        dinv[i] = rsqrtf((float)(c + 1));
        run += c;
    }
    if (t == 1023) rowptr[NN] = run;               // == NE
}

__global__ void fill_kernel(const int* __restrict__ src, const int* __restrict__ dst,
                            int* __restrict__ cursor, int* __restrict__ csr) {
    int e = blockIdx.x * blockDim.x + threadIdx.x;
    if (e < NE) {
        int d = dst[e];
        int pos = atomicAdd(&cursor[d], 1);
        csr[pos] = src[e];
    }
}

// ---------------- propagation: hout = D^-1/2 (A+I) D^-1/2 hin ; out (+)= COEF*hout
// one 64-lane wave per node, lane = feature
template <int STEP, bool STORE>
__global__ void prop_kernel(const float* __restrict__ hin, float* __restrict__ hout,
                            float* __restrict__ out, const float* __restrict__ x,
                            const float* __restrict__ dinv,
                            const int* __restrict__ rowptr, const int* __restrict__ csr) {
    const int wid  = (blockIdx.x * blockDim.x + threadIdx.x) >> 6;
    const int lane = threadIdx.x & 63;
    if (wid >= NN) return;
    const int beg = rowptr[wid];
    const int endp = rowptr[wid + 1];
    float acc = 0.f;
    for (int e = beg; e < endp; ++e) {
        int s = csr[e];
        acc = fmaf(dinv[s], hin[s * HID + lane], acc);
    }
    const float dv = dinv[wid];
    const float hv = dv * (acc + dv * hin[wid * HID + lane]);
    if (STORE) hout[wid * HID + lane] = hv;
    const int o = wid * HID + lane;
    if (STEP == 0) out[o] = ALPHA * x[o] + COEF * hv;
    else           out[o] = out[o] + COEF * hv;
}

// ---------------- SimpleConv(mean) of relu(out) + residual + relu ----------------
__global__ void final_kernel(const float* __restrict__ out, const float* __restrict__ x,
                             const int* __restrict__ rowptr, const int* __restrict__ csr,
                             float* __restrict__ res) {
    const int wid  = (blockIdx.x * blockDim.x + threadIdx.x) >> 6;
    const int lane = threadIdx.x & 63;
    if (wid >= NN) return;
    const int beg = rowptr[wid];
    const int endp = rowptr[wid + 1];
    float sum = 0.f;
    for (int e = beg; e < endp; ++e) {
        int s = csr[e];
        sum += fmaxf(out[s * HID + lane], 0.f);
    }
    const float cntf = (float)(endp - beg);
    const float mean = sum / fmaxf(cntf, 1.f);
    const int o = wid * HID + lane;
    res[o] = fmaxf(mean + x[o], 0.f);
}

extern "C" void kernel_launch(void* const* d_in, const int* in_sizes, int n_in,
                              void* d_out, int out_size, void* d_ws, size_t ws_size,
                              hipStream_t stream) {
    const float* x  = (const float*)d_in[0];
    const int* ei   = (const int*)d_in[1];      // (2, NE) row-major: [src | dst]
    const int* srcp = ei;
    const int* dstp = ei + NE;
    float* resp     = (float*)d_out;

    // workspace carve-up (256B aligned)
    size_t off = 0;
    auto carve = [&](size_t bytes) { size_t p = off; off = (off + bytes + 255) & ~(size_t)255; return p; };
    char* ws = (char*)d_ws;
    int*   cnt    = (int*)  (ws + carve((size_t)NN * 4));
    int*   rowptr = (int*)  (ws + carve((size_t)(NN + 1) * 4));
    int*   cursor = (int*)  (ws + carve((size_t)NN * 4));
    float* dinv   = (float*)(ws + carve((size_t)NN * 4));
    int*   csr    = (int*)  (ws + carve((size_t)NE * 4));
    float* h1     = (float*)(ws + carve((size_t)NN * HID * 4));
    float* h2     = (float*)(ws + carve((size_t)NN * HID * 4));
    float* outb   = (float*)(ws + carve((size_t)NN * HID * 4));
    (void)ws_size; (void)n_in; (void)in_sizes; (void)out_size;

    hipMemsetAsync(cnt, 0, (size_t)NN * 4, stream);

    const int eblk = 256;
    const int egrid = (NE + eblk - 1) / eblk;       // 6250
    count_kernel<<<egrid, eblk, 0, stream>>>(dstp, cnt);
    scan_kernel<<<1, 1024, 0, stream>>>(cnt, rowptr, cursor, dinv);
    fill_kernel<<<egrid, eblk, 0, stream>>>(srcp, dstp, cursor, csr);

    const int nblk = 256;                            // 4 waves/block, 1 node/wave
    const int ngrid = (NN + 3) / 4;                  // 25000
    prop_kernel<0, true ><<<ngrid, nblk, 0, stream>>>(x,  h1, outb, x, dinv, rowptr, csr);
    prop_kernel<1, true ><<<ngrid, nblk, 0, stream>>>(h1, h2, outb, x, dinv, rowptr, csr);
    prop_kernel<2, false><<<ngrid, nblk, 0, stream>>>(h2, nullptr, outb, x, dinv, rowptr, csr);
    final_kernel<<<ngrid, nblk, 0, stream>>>(outb, x, rowptr, csr, resp);
}

// Round 2
// 871.242 us; speedup vs baseline: 1.2992x; 1.2992x over previous
//
#include <hip/hip_runtime.h>
#include <hip/hip_bf16.h>

#define NN 100000
#define NE 1600000
#define HID 64
#define ALPHA 0.1f
#define COEF 0.3f   // (1-ALPHA)/K

#define SCAN_BLK 1024
#define SCAN_ELEMS 4096                         // 4 per thread
#define SCAN_NB ((NN + SCAN_ELEMS - 1) / SCAN_ELEMS)   // 25

// ---------------- CSR build ----------------

__global__ void count_kernel(const int* __restrict__ dst, int* __restrict__ cnt) {
    int e = blockIdx.x * blockDim.x + threadIdx.x;
    if (e < NE) atomicAdd(&cnt[dst[e]], 1);
}

// Phase A: per-block sum of cnt chunk -> blockSums[b]
__global__ void scanA_kernel(const int* __restrict__ cnt, int* __restrict__ blockSums) {
    __shared__ int red[SCAN_BLK / 64];
    const int b = blockIdx.x, t = threadIdx.x;
    const int idx = b * SCAN_ELEMS + t * 4;
    int s = 0;
    if (idx + 3 < NN) {
        int4 v = *reinterpret_cast<const int4*>(&cnt[idx]);
        s = v.x + v.y + v.z + v.w;
    } else {
        for (int i = 0; i < 4; ++i) if (idx + i < NN) s += cnt[idx + i];
    }
    for (int o = 32; o > 0; o >>= 1) s += __shfl_down(s, o, 64);
    if ((t & 63) == 0) red[t >> 6] = s;
    __syncthreads();
    if (t < 64) {
        s = (t < SCAN_BLK / 64) ? red[t] : 0;
        for (int o = 32; o > 0; o >>= 1) s += __shfl_down(s, o, 64);
        if (t == 0) blockSums[b] = s;
    }
}

// Phase C: block-local exclusive scan + block offset -> rowptr/cursor/dinv
__global__ void scanC_kernel(const int* __restrict__ cnt, const int* __restrict__ blockSums,
                             int* __restrict__ rowptr, int* __restrict__ cursor,
                             float* __restrict__ dinv) {
    __shared__ int tsum[SCAN_BLK];
    __shared__ int s_off;
    const int b = blockIdx.x, t = threadIdx.x;
    const int idx = b * SCAN_ELEMS + t * 4;
    int v0 = 0, v1 = 0, v2 = 0, v3 = 0;
    if (idx + 3 < NN) {
        int4 q = *reinterpret_cast<const int4*>(&cnt[idx]);
        v0 = q.x; v1 = q.y; v2 = q.z; v3 = q.w;
    } else {
        if (idx + 0 < NN) v0 = cnt[idx + 0];
        if (idx + 1 < NN) v1 = cnt[idx + 1];
        if (idx + 2 < NN) v2 = cnt[idx + 2];
        if (idx + 3 < NN) v3 = cnt[idx + 3];
    }
    tsum[t] = v0 + v1 + v2 + v3;
    if (t == 0) {
        int o = 0;
        for (int i = 0; i < b; ++i) o += blockSums[i];
        s_off = o;
    }
    __syncthreads();
    for (int off = 1; off < SCAN_BLK; off <<= 1) {
        int val = (t >= off) ? tsum[t - off] : 0;
        __syncthreads();
        if (t >= off) tsum[t] += val;
        __syncthreads();
    }
    int run = s_off + ((t > 0) ? tsum[t - 1] : 0);
    if (idx + 3 < NN) {
        int4 rp; float4 dv;
        rp.x = run;            dv.x = rsqrtf((float)(v0 + 1)); run += v0;
        rp.y = run;            dv.y = rsqrtf((float)(v1 + 1)); run += v1;
        rp.z = run;            dv.z = rsqrtf((float)(v2 + 1)); run += v2;
        rp.w = run;            dv.w = rsqrtf((float)(v3 + 1)); run += v3;
        *reinterpret_cast<int4*>(&rowptr[idx]) = rp;
        *reinterpret_cast<int4*>(&cursor[idx]) = rp;
        *reinterpret_cast<float4*>(&dinv[idx]) = dv;
    } else {
        int vv[4] = {v0, v1, v2, v3};
        for (int i = 0; i < 4; ++i) {
            if (idx + i < NN) {
                rowptr[idx + i] = run;
                cursor[idx + i] = run;
                dinv[idx + i]   = rsqrtf((float)(vv[i] + 1));
                run += vv[i];
            }
        }
    }
    if (b == 0 && t == 0) rowptr[NN] = NE;
}

__global__ void fill_kernel(const int* __restrict__ src, const int* __restrict__ dst,
                            int* __restrict__ cursor, int* __restrict__ csr) {
    int e = blockIdx.x * blockDim.x + threadIdx.x;
    if (e < NE) {
        int d = dst[e];
        int pos = atomicAdd(&cursor[d], 1);
        csr[pos] = src[e];
    }
}

// ---------------- propagation: hout = D^-1/2 (A+I) D^-1/2 hin ; out (+)= COEF*hout
// one 64-lane wave per node, lane = feature
template <int STEP, bool STORE>
__global__ void prop_kernel(const float* __restrict__ hin, float* __restrict__ hout,
                            float* __restrict__ out, const float* __restrict__ x,
                            const float* __restrict__ dinv,
                            const int* __restrict__ rowptr, const int* __restrict__ csr) {
    const int wid  = (blockIdx.x * blockDim.x + threadIdx.x) >> 6;
    const int lane = threadIdx.x & 63;
    if (wid >= NN) return;
    const int beg = rowptr[wid];
    const int endp = rowptr[wid + 1];
    float acc = 0.f;
    for (int e = beg; e < endp; ++e) {
        int s = csr[e];
        acc = fmaf(dinv[s], hin[s * HID + lane], acc);
    }
    const float dv = dinv[wid];
    const float hv = dv * (acc + dv * hin[wid * HID + lane]);
    if (STORE) hout[wid * HID + lane] = hv;
    const int o = wid * HID + lane;
    if (STEP == 0) out[o] = ALPHA * x[o] + COEF * hv;
    else           out[o] = out[o] + COEF * hv;
}

// ---------------- SimpleConv(mean) of relu(out) + residual + relu ----------------
__global__ void final_kernel(const float* __restrict__ out, const float* __restrict__ x,
                             const int* __restrict__ rowptr, const int* __restrict__ csr,
                             float* __restrict__ res) {
    const int wid  = (blockIdx.x * blockDim.x + threadIdx.x) >> 6;
    const int lane = threadIdx.x & 63;
    if (wid >= NN) return;
    const int beg = rowptr[wid];
    const int endp = rowptr[wid + 1];
    float sum = 0.f;
    for (int e = beg; e < endp; ++e) {
        int s = csr[e];
        sum += fmaxf(out[s * HID + lane], 0.f);
    }
    const float cntf = (float)(endp - beg);
    const float mean = sum / fmaxf(cntf, 1.f);
    const int o = wid * HID + lane;
    res[o] = fmaxf(mean + x[o], 0.f);
}

extern "C" void kernel_launch(void* const* d_in, const int* in_sizes, int n_in,
                              void* d_out, int out_size, void* d_ws, size_t ws_size,
                              hipStream_t stream) {
    const float* x  = (const float*)d_in[0];
    const int* ei   = (const int*)d_in[1];      // (2, NE) row-major: [src | dst]
    const int* srcp = ei;
    const int* dstp = ei + NE;
    float* resp     = (float*)d_out;

    // workspace carve-up (256B aligned)
    size_t off = 0;
    auto carve = [&](size_t bytes) { size_t p = off; off = (off + bytes + 255) & ~(size_t)255; return p; };
    char* ws = (char*)d_ws;
    int*   cnt    = (int*)  (ws + carve((size_t)NN * 4));
    int*   rowptr = (int*)  (ws + carve((size_t)(NN + 1) * 4));
    int*   cursor = (int*)  (ws + carve((size_t)NN * 4));
    float* dinv   = (float*)(ws + carve((size_t)NN * 4));
    int*   bsums  = (int*)  (ws + carve((size_t)SCAN_NB * 4));
    int*   csr    = (int*)  (ws + carve((size_t)NE * 4));
    float* h1     = (float*)(ws + carve((size_t)NN * HID * 4));
    float* h2     = (float*)(ws + carve((size_t)NN * HID * 4));
    float* outb   = (float*)(ws + carve((size_t)NN * HID * 4));
    (void)ws_size; (void)n_in; (void)in_sizes; (void)out_size;

    hipMemsetAsync(cnt, 0, (size_t)NN * 4, stream);

    const int eblk = 256;
    const int egrid = (NE + eblk - 1) / eblk;       // 6250
    count_kernel<<<egrid, eblk, 0, stream>>>(dstp, cnt);
    scanA_kernel<<<SCAN_NB, SCAN_BLK, 0, stream>>>(cnt, bsums);
    scanC_kernel<<<SCAN_NB, SCAN_BLK, 0, stream>>>(cnt, bsums, rowptr, cursor, dinv);
    fill_kernel<<<egrid, eblk, 0, stream>>>(srcp, dstp, cursor, csr);

    const int nblk = 256;                            // 4 waves/block, 1 node/wave
    const int ngrid = (NN + 3) / 4;                  // 25000
    prop_kernel<0, true ><<<ngrid, nblk, 0, stream>>>(x,  h1, outb, x, dinv, rowptr, csr);
    prop_kernel<1, true ><<<ngrid, nblk, 0, stream>>>(h1, h2, outb, x, dinv, rowptr, csr);
    prop_kernel<2, false><<<ngrid, nblk, 0, stream>>>(h2, nullptr, outb, x, dinv, rowptr, csr);
    final_kernel<<<ngrid, nblk, 0, stream>>>(outb, x, rowptr, csr, resp);
}

// Round 3
// 463.313 us; speedup vs baseline: 2.4432x; 1.8805x over previous
//
#include <hip/hip_runtime.h>
#include <hip/hip_bf16.h>

#define NN 100000
#define NE 1600000
#define HID 64
#define ALPHA 0.1f
#define COEF 0.3f   // (1-ALPHA)/K

#define SCAN_BLK 1024
#define SCAN_ELEMS 4096                         // 4 per thread
#define SCAN_NB ((NN + SCAN_ELEMS - 1) / SCAN_ELEMS)   // 25

__device__ __forceinline__ float bf2f(unsigned short u) {
    union { unsigned int i; float f; } v; v.i = ((unsigned int)u) << 16; return v.f;
}
__device__ __forceinline__ unsigned short f2bf(float f) {
    union { float f; unsigned int i; } v; v.f = f;
    unsigned int r = v.i + 0x7FFF + ((v.i >> 16) & 1);   // round-nearest-even
    return (unsigned short)(r >> 16);
}

// ---------------- CSR build ----------------

__global__ void count_kernel(const int* __restrict__ dst, int* __restrict__ cnt) {
    int e = blockIdx.x * blockDim.x + threadIdx.x;
    if (e < NE) atomicAdd(&cnt[dst[e]], 1);
}

__global__ void scanA_kernel(const int* __restrict__ cnt, int* __restrict__ blockSums) {
    __shared__ int red[SCAN_BLK / 64];
    const int b = blockIdx.x, t = threadIdx.x;
    const int idx = b * SCAN_ELEMS + t * 4;
    int s = 0;
    if (idx + 3 < NN) {
        int4 v = *reinterpret_cast<const int4*>(&cnt[idx]);
        s = v.x + v.y + v.z + v.w;
    } else {
        for (int i = 0; i < 4; ++i) if (idx + i < NN) s += cnt[idx + i];
    }
    for (int o = 32; o > 0; o >>= 1) s += __shfl_down(s, o, 64);
    if ((t & 63) == 0) red[t >> 6] = s;
    __syncthreads();
    if (t < 64) {
        s = (t < SCAN_BLK / 64) ? red[t] : 0;
        for (int o = 32; o > 0; o >>= 1) s += __shfl_down(s, o, 64);
        if (t == 0) blockSums[b] = s;
    }
}

__global__ void scanC_kernel(const int* __restrict__ cnt, const int* __restrict__ blockSums,
                             int* __restrict__ rowptr, int* __restrict__ cursor,
                             float* __restrict__ dinv) {
    __shared__ int tsum[SCAN_BLK];
    __shared__ int s_off;
    const int b = blockIdx.x, t = threadIdx.x;
    const int idx = b * SCAN_ELEMS + t * 4;
    int v0 = 0, v1 = 0, v2 = 0, v3 = 0;
    if (idx + 3 < NN) {
        int4 q = *reinterpret_cast<const int4*>(&cnt[idx]);
        v0 = q.x; v1 = q.y; v2 = q.z; v3 = q.w;
    } else {
        if (idx + 0 < NN) v0 = cnt[idx + 0];
        if (idx + 1 < NN) v1 = cnt[idx + 1];
        if (idx + 2 < NN) v2 = cnt[idx + 2];
        if (idx + 3 < NN) v3 = cnt[idx + 3];
    }
    tsum[t] = v0 + v1 + v2 + v3;
    if (t == 0) {
        int o = 0;
        for (int i = 0; i < b; ++i) o += blockSums[i];
        s_off = o;
    }
    __syncthreads();
    for (int off = 1; off < SCAN_BLK; off <<= 1) {
        int val = (t >= off) ? tsum[t - off] : 0;
        __syncthreads();
        if (t >= off) tsum[t] += val;
        __syncthreads();
    }
    int run = s_off + ((t > 0) ? tsum[t - 1] : 0);
    if (idx + 3 < NN) {
        int4 rp; float4 dv;
        rp.x = run; dv.x = rsqrtf((float)(v0 + 1)); run += v0;
        rp.y = run; dv.y = rsqrtf((float)(v1 + 1)); run += v1;
        rp.z = run; dv.z = rsqrtf((float)(v2 + 1)); run += v2;
        rp.w = run; dv.w = rsqrtf((float)(v3 + 1)); run += v3;
        *reinterpret_cast<int4*>(&rowptr[idx]) = rp;
        *reinterpret_cast<int4*>(&cursor[idx]) = rp;
        *reinterpret_cast<float4*>(&dinv[idx]) = dv;
    } else {
        int vv[4] = {v0, v1, v2, v3};
        for (int i = 0; i < 4; ++i) {
            if (idx + i < NN) {
                rowptr[idx + i] = run;
                cursor[idx + i] = run;
                dinv[idx + i]   = rsqrtf((float)(vv[i] + 1));
                run += vv[i];
            }
        }
    }
    if (b == 0 && t == 0) rowptr[NN] = NE;
}

__global__ void fill_kernel(const int* __restrict__ src, const int* __restrict__ dst,
                            int* __restrict__ cursor, int* __restrict__ csr) {
    int e = blockIdx.x * blockDim.x + threadIdx.x;
    if (e < NE) {
        int d = dst[e];
        int pos = atomicAdd(&cursor[d], 1);
        csr[pos] = src[e];
    }
}

// g0 = bf16(dinv[v] * x[v])  — 4 elems/thread
__global__ void g0_kernel(const float* __restrict__ x, const float* __restrict__ dinv,
                          unsigned short* __restrict__ g0) {
    int i = blockIdx.x * blockDim.x + threadIdx.x;          // elem-quad index
    if (i >= NN * HID / 4) return;
    float dv = dinv[(i * 4) >> 6];
    float4 v = *reinterpret_cast<const float4*>(&x[i * 4]);
    ushort4 u;
    u.x = f2bf(dv * v.x); u.y = f2bf(dv * v.y);
    u.z = f2bf(dv * v.z); u.w = f2bf(dv * v.w);
    *reinterpret_cast<ushort4*>(&g0[i * 4]) = u;
}

// ---------------- propagation ----------------
// g holds dinv*h (bf16). h_next = dv*(sum_{s in N(v)} g[s] + g[v]);
// gout = dv*h_next ; out (+)= COEF*h_next.
// One wave per node. Lane layout: grp=lane>>4 (edge slot), fl=lane&15 (4 features).
template <int STEP>
__global__ void prop_kernel(const unsigned short* __restrict__ gin,
                            unsigned short* __restrict__ gout,
                            float* __restrict__ out, const float* __restrict__ x,
                            const float* __restrict__ dinv,
                            const int* __restrict__ rowptr, const int* __restrict__ csr,
                            unsigned short* __restrict__ routb) {
    const int wid  = (blockIdx.x * blockDim.x + threadIdx.x) >> 6;
    if (wid >= NN) return;
    const int lane = threadIdx.x & 63;
    const int grp  = lane >> 4;
    const int fl   = lane & 15;
    const int beg  = rowptr[wid];
    const int endp = rowptr[wid + 1];

    float4 acc = make_float4(0.f, 0.f, 0.f, 0.f);
    int e = beg + grp;
    // 2-deep unroll: 8 gathers in flight per wave
    for (; e + 4 < endp; e += 8) {
        int s0 = csr[e];
        int s1 = csr[e + 4];
        ushort4 u0 = *reinterpret_cast<const ushort4*>(&gin[s0 * HID + fl * 4]);
        ushort4 u1 = *reinterpret_cast<const ushort4*>(&gin[s1 * HID + fl * 4]);
        acc.x += bf2f(u0.x) + bf2f(u1.x);
        acc.y += bf2f(u0.y) + bf2f(u1.y);
        acc.z += bf2f(u0.z) + bf2f(u1.z);
        acc.w += bf2f(u0.w) + bf2f(u1.w);
    }
    if (e < endp) {
        int s0 = csr[e];
        ushort4 u0 = *reinterpret_cast<const ushort4*>(&gin[s0 * HID + fl * 4]);
        acc.x += bf2f(u0.x); acc.y += bf2f(u0.y);
        acc.z += bf2f(u0.z); acc.w += bf2f(u0.w);
    }
    // cross-group reduce (4 groups)
    acc.x += __shfl_xor(acc.x, 16, 64); acc.x += __shfl_xor(acc.x, 32, 64);
    acc.y += __shfl_xor(acc.y, 16, 64); acc.y += __shfl_xor(acc.y, 32, 64);
    acc.z += __shfl_xor(acc.z, 16, 64); acc.z += __shfl_xor(acc.z, 32, 64);
    acc.w += __shfl_xor(acc.w, 16, 64); acc.w += __shfl_xor(acc.w, 32, 64);

    const float dv = dinv[wid];
    ushort4 us = *reinterpret_cast<const ushort4*>(&gin[wid * HID + fl * 4]);
    float4 h;
    h.x = dv * (acc.x + bf2f(us.x));
    h.y = dv * (acc.y + bf2f(us.y));
    h.z = dv * (acc.z + bf2f(us.z));
    h.w = dv * (acc.w + bf2f(us.w));

    const int o = wid * HID + fl * 4;
    if (STEP < 2) {
        if (grp == 0) {
            ushort4 gn;
            gn.x = f2bf(dv * h.x); gn.y = f2bf(dv * h.y);
            gn.z = f2bf(dv * h.z); gn.w = f2bf(dv * h.w);
            *reinterpret_cast<ushort4*>(&gout[o]) = gn;
        }
    }
    if (STEP == 0) {
        float4 xr = *reinterpret_cast<const float4*>(&x[o]);
        if (grp == 0) {
            float4 ov;
            ov.x = ALPHA * xr.x + COEF * h.x;
            ov.y = ALPHA * xr.y + COEF * h.y;
            ov.z = ALPHA * xr.z + COEF * h.z;
            ov.w = ALPHA * xr.w + COEF * h.w;
            *reinterpret_cast<float4*>(&out[o]) = ov;
        }
    } else if (STEP == 1) {
        float4 ov = *reinterpret_cast<const float4*>(&out[o]);
        if (grp == 0) {
            ov.x += COEF * h.x; ov.y += COEF * h.y;
            ov.z += COEF * h.z; ov.w += COEF * h.w;
            *reinterpret_cast<float4*>(&out[o]) = ov;
        }
    } else {
        float4 ov = *reinterpret_cast<const float4*>(&out[o]);
        if (grp == 0) {
            ushort4 r;
            r.x = f2bf(fmaxf(ov.x + COEF * h.x, 0.f));
            r.y = f2bf(fmaxf(ov.y + COEF * h.y, 0.f));
            r.z = f2bf(fmaxf(ov.z + COEF * h.z, 0.f));
            r.w = f2bf(fmaxf(ov.w + COEF * h.w, 0.f));
            *reinterpret_cast<ushort4*>(&routb[o]) = r;
        }
    }
}

// ---------------- SimpleConv(mean) of relu(out) + residual + relu ----------------
__global__ void final_kernel(const unsigned short* __restrict__ routb,
                             const float* __restrict__ x,
                             const int* __restrict__ rowptr, const int* __restrict__ csr,
                             float* __restrict__ res) {
    const int wid  = (blockIdx.x * blockDim.x + threadIdx.x) >> 6;
    if (wid >= NN) return;
    const int lane = threadIdx.x & 63;
    const int grp  = lane >> 4;
    const int fl   = lane & 15;
    const int beg  = rowptr[wid];
    const int endp = rowptr[wid + 1];

    float4 acc = make_float4(0.f, 0.f, 0.f, 0.f);
    int e = beg + grp;
    for (; e + 4 < endp; e += 8) {
        int s0 = csr[e];
        int s1 = csr[e + 4];
        ushort4 u0 = *reinterpret_cast<const ushort4*>(&routb[s0 * HID + fl * 4]);
        ushort4 u1 = *reinterpret_cast<const ushort4*>(&routb[s1 * HID + fl * 4]);
        acc.x += bf2f(u0.x) + bf2f(u1.x);
        acc.y += bf2f(u0.y) + bf2f(u1.y);
        acc.z += bf2f(u0.z) + bf2f(u1.z);
        acc.w += bf2f(u0.w) + bf2f(u1.w);
    }
    if (e < endp) {
        int s0 = csr[e];
        ushort4 u0 = *reinterpret_cast<const ushort4*>(&routb[s0 * HID + fl * 4]);
        acc.x += bf2f(u0.x); acc.y += bf2f(u0.y);
        acc.z += bf2f(u0.z); acc.w += bf2f(u0.w);
    }
    acc.x += __shfl_xor(acc.x, 16, 64); acc.x += __shfl_xor(acc.x, 32, 64);
    acc.y += __shfl_xor(acc.y, 16, 64); acc.y += __shfl_xor(acc.y, 32, 64);
    acc.z += __shfl_xor(acc.z, 16, 64); acc.z += __shfl_xor(acc.z, 32, 64);
    acc.w += __shfl_xor(acc.w, 16, 64); acc.w += __shfl_xor(acc.w, 32, 64);

    if (grp == 0) {
        const float inv = 1.f / fmaxf((float)(endp - beg), 1.f);
        const int o = wid * HID + fl * 4;
        float4 xr = *reinterpret_cast<const float4*>(&x[o]);
        float4 rv;
        rv.x = fmaxf(acc.x * inv + xr.x, 0.f);
        rv.y = fmaxf(acc.y * inv + xr.y, 0.f);
        rv.z = fmaxf(acc.z * inv + xr.z, 0.f);
        rv.w = fmaxf(acc.w * inv + xr.w, 0.f);
        *reinterpret_cast<float4*>(&res[o]) = rv;
    }
}

extern "C" void kernel_launch(void* const* d_in, const int* in_sizes, int n_in,
                              void* d_out, int out_size, void* d_ws, size_t ws_size,
                              hipStream_t stream) {
    const float* x  = (const float*)d_in[0];
    const int* ei   = (const int*)d_in[1];      // (2, NE): [src | dst]
    const int* srcp = ei;
    const int* dstp = ei + NE;
    float* resp     = (float*)d_out;

    size_t off = 0;
    auto carve = [&](size_t bytes) { size_t p = off; off = (off + bytes + 255) & ~(size_t)255; return p; };
    char* ws = (char*)d_ws;
    int*   cnt    = (int*)  (ws + carve((size_t)NN * 4));
    int*   rowptr = (int*)  (ws + carve((size_t)(NN + 1) * 4));
    int*   cursor = (int*)  (ws + carve((size_t)NN * 4));
    float* dinv   = (float*)(ws + carve((size_t)NN * 4));
    int*   bsums  = (int*)  (ws + carve((size_t)SCAN_NB * 4));
    int*   csr    = (int*)  (ws + carve((size_t)NE * 4));
    unsigned short* gA    = (unsigned short*)(ws + carve((size_t)NN * HID * 2));
    unsigned short* gB    = (unsigned short*)(ws + carve((size_t)NN * HID * 2));
    unsigned short* routb = (unsigned short*)(ws + carve((size_t)NN * HID * 2));
    float* outb   = (float*)(ws + carve((size_t)NN * HID * 4));
    (void)ws_size; (void)n_in; (void)in_sizes; (void)out_size;

    hipMemsetAsync(cnt, 0, (size_t)NN * 4, stream);

    const int eblk = 256;
    const int egrid = (NE + eblk - 1) / eblk;       // 6250
    count_kernel<<<egrid, eblk, 0, stream>>>(dstp, cnt);
    scanA_kernel<<<SCAN_NB, SCAN_BLK, 0, stream>>>(cnt, bsums);
    scanC_kernel<<<SCAN_NB, SCAN_BLK, 0, stream>>>(cnt, bsums, rowptr, cursor, dinv);
    fill_kernel<<<egrid, eblk, 0, stream>>>(srcp, dstp, cursor, csr);
    g0_kernel<<<(NN * HID / 4 + 255) / 256, 256, 0, stream>>>(x, dinv, gA);

    const int nblk = 256;                            // 4 nodes/block (1 wave each)
    const int ngrid = (NN + 3) / 4;                  // 25000
    prop_kernel<0><<<ngrid, nblk, 0, stream>>>(gA, gB, outb, x, dinv, rowptr, csr, nullptr);
    prop_kernel<1><<<ngrid, nblk, 0, stream>>>(gB, gA, outb, x, dinv, rowptr, csr, nullptr);
    prop_kernel<2><<<ngrid, nblk, 0, stream>>>(gA, nullptr, outb, x, dinv, rowptr, csr, routb);
    final_kernel<<<ngrid, nblk, 0, stream>>>(routb, x, rowptr, csr, resp);
}

// Round 5
// 323.455 us; speedup vs baseline: 3.4996x; 1.4324x over previous
//
#include <hip/hip_runtime.h>
#include <hip/hip_bf16.h>

#define NN 100000
#define NE 1600000
#define HID 64
#define ALPHA 0.1f
#define COEF 0.3f   // (1-ALPHA)/K

#define NBK 196            // buckets of 512 nodes: dst>>9
#define SBLK 256           // blocks for hist/scatter passes
#define EB_PER_BLK (NE / SBLK)   // 6250

__device__ __forceinline__ float bf2f(unsigned short u) {
    union { unsigned int i; float f; } v; v.i = ((unsigned int)u) << 16; return v.f;
}
__device__ __forceinline__ unsigned short f2bf(float f) {
    union { float f; unsigned int i; } v; v.f = f;
    unsigned int r = v.i + 0x7FFF + ((v.i >> 16) & 1);
    return (unsigned short)(r >> 16);
}
__device__ __forceinline__ void acc2(float& lo, float& hi, unsigned int u) {
    union { unsigned int i; float f; } a, b;
    a.i = u << 16; b.i = u & 0xFFFF0000u;
    lo += a.f; hi += b.f;
}
__device__ __forceinline__ void up2(float& lo, float& hi, unsigned int u) {
    union { unsigned int i; float f; } a, b;
    a.i = u << 16; b.i = u & 0xFFFF0000u;
    lo = a.f; hi = b.f;
}
__device__ __forceinline__ unsigned int pk2(float lo, float hi) {
    return (unsigned int)f2bf(lo) | ((unsigned int)f2bf(hi) << 16);
}

// ---------------- bucketed CSR build (no global atomics) ----------------

// Pass A: per-block bucket histogram -> hist[j*SBLK + b]
__global__ void histA_kernel(const int* __restrict__ dst, int* __restrict__ hist) {
    __shared__ int cnt[NBK];
    const int b = blockIdx.x, t = threadIdx.x;
    for (int i = t; i < NBK; i += 256) cnt[i] = 0;
    __syncthreads();
    const int beg = b * EB_PER_BLK, end = beg + EB_PER_BLK;
    for (int e = beg + t; e < end; e += 256)
        atomicAdd(&cnt[dst[e] >> 9], 1);
    __syncthreads();
    for (int i = t; i < NBK; i += 256)
        hist[i * SBLK + b] = cnt[i];
}

// Exclusive scan of hist (NBK*SBLK = 50176 = 1024*49 elements), in place.
__global__ void scanH_kernel(int* __restrict__ hist) {
    __shared__ int tsum[1024];
    const int t = threadIdx.x;
    const int base = t * 49;
    int s = 0;
    for (int i = 0; i < 49; ++i) s += hist[base + i];
    tsum[t] = s;
    __syncthreads();
    for (int off = 1; off < 1024; off <<= 1) {
        int v = (t >= off) ? tsum[t - off] : 0;
        __syncthreads();
        if (t >= off) tsum[t] += v;
        __syncthreads();
    }
    int run = (t == 0) ? 0 : tsum[t - 1];
    for (int i = 0; i < 49; ++i) {
        int v = hist[base + i];
        hist[base + i] = run;
        run += v;
    }
}

// Pass B: scatter packed (src<<9 | dst&511) into per-(bucket,block) runs.
__global__ void scatterB_kernel(const int* __restrict__ src, const int* __restrict__ dst,
                                const int* __restrict__ hist, unsigned int* __restrict__ buck) {
    __shared__ int cur[NBK];
    const int b = blockIdx.x, t = threadIdx.x;
    for (int i = t; i < NBK; i += 256) cur[i] = hist[i * SBLK + b];
    __syncthreads();
    const int beg = b * EB_PER_BLK, end = beg + EB_PER_BLK;
    for (int e = beg + t; e < end; e += 256) {
        int d = dst[e];
        int pos = atomicAdd(&cur[d >> 9], 1);
        buck[pos] = ((unsigned int)src[e] << 9) | (unsigned int)(d & 511);
    }
}

// Pass C: per-bucket local sort -> rowptr, dinv, csr (all writes block-exclusive).
__global__ void bucketC_kernel(const unsigned int* __restrict__ buck, const int* __restrict__ hist,
                               int* __restrict__ rowptr, float* __restrict__ dinv,
                               int* __restrict__ csr) {
    __shared__ int cnt[512];
    __shared__ int excl[512];
    const int j = blockIdx.x, t = threadIdx.x;
    const int ebeg = hist[j * SBLK];
    const int eend = (j == NBK - 1) ? NE : hist[(j + 1) * SBLK];
    cnt[t] = 0;
    __syncthreads();
    for (int e = ebeg + t; e < eend; e += 512)
        atomicAdd(&cnt[buck[e] & 511], 1);
    __syncthreads();
    excl[t] = cnt[t];
    __syncthreads();
    for (int off = 1; off < 512; off <<= 1) {
        int v = (t >= off) ? excl[t - off] : 0;
        __syncthreads();
        if (t >= off) excl[t] += v;
        __syncthreads();
    }
    const int my_excl = (t == 0) ? 0 : excl[t - 1];
    const int node = j * 512 + t;
    if (node < NN) {
        rowptr[node] = ebeg + my_excl;
        dinv[node] = rsqrtf((float)(cnt[t] + 1));
    }
    if (j == NBK - 1 && t == 0) rowptr[NN] = NE;
    __syncthreads();
    cnt[t] = ebeg + my_excl;     // cursor
    __syncthreads();
    for (int e = ebeg + t; e < eend; e += 512) {
        unsigned int v = buck[e];
        int pos = atomicAdd(&cnt[v & 511], 1);
        csr[pos] = (int)(v >> 9);
    }
}

// g0 = bf16(dinv[v] * x[v])
__global__ void g0_kernel(const float* __restrict__ x, const float* __restrict__ dinv,
                          unsigned short* __restrict__ g0) {
    int i = blockIdx.x * blockDim.x + threadIdx.x;
    if (i >= NN * HID / 4) return;
    float dv = dinv[(i * 4) >> 6];
    float4 v = *reinterpret_cast<const float4*>(&x[i * 4]);
    ushort4 u;
    u.x = f2bf(dv * v.x); u.y = f2bf(dv * v.y);
    u.z = f2bf(dv * v.z); u.w = f2bf(dv * v.w);
    *reinterpret_cast<ushort4*>(&g0[i * 4]) = u;
}

// ---------------- propagation ----------------
// g = dinv*h (bf16). h_next = dv*(sum g[s] + g[v]); gout = dv*h_next; out (+)= COEF*h_next.
// One wave/node. grp=lane>>3 (8 edge slots), fl=lane&7 (8 bf16 = 16B per lane).
template <int STEP>
__global__ void prop_kernel(const unsigned short* __restrict__ gin,
                            unsigned short* __restrict__ gout,
                            float* __restrict__ out, const float* __restrict__ x,
                            const float* __restrict__ dinv,
                            const int* __restrict__ rowptr, const int* __restrict__ csr,
                            unsigned short* __restrict__ routb) {
    const int wid = (blockIdx.x * blockDim.x + threadIdx.x) >> 6;
    if (wid >= NN) return;
    const int lane = threadIdx.x & 63;
    const int grp = lane >> 3;
    const int fl  = lane & 7;
    const int beg = rowptr[wid], endp = rowptr[wid + 1];
    float acc[8];
#pragma unroll
    for (int i = 0; i < 8; ++i) acc[i] = 0.f;
    int e = beg + grp;
    for (; e + 8 < endp; e += 16) {       // 16 gathers in flight per wave
        int s0 = csr[e], s1 = csr[e + 8];
        uint4 q0 = *reinterpret_cast<const uint4*>(&gin[s0 * HID + fl * 8]);
        uint4 q1 = *reinterpret_cast<const uint4*>(&gin[s1 * HID + fl * 8]);
        acc2(acc[0], acc[1], q0.x); acc2(acc[2], acc[3], q0.y);
        acc2(acc[4], acc[5], q0.z); acc2(acc[6], acc[7], q0.w);
        acc2(acc[0], acc[1], q1.x); acc2(acc[2], acc[3], q1.y);
        acc2(acc[4], acc[5], q1.z); acc2(acc[6], acc[7], q1.w);
    }
    if (e < endp) {
        int s0 = csr[e];
        uint4 q0 = *reinterpret_cast<const uint4*>(&gin[s0 * HID + fl * 8]);
        acc2(acc[0], acc[1], q0.x); acc2(acc[2], acc[3], q0.y);
        acc2(acc[4], acc[5], q0.z); acc2(acc[6], acc[7], q0.w);
    }
#pragma unroll
    for (int i = 0; i < 8; ++i) {
        acc[i] += __shfl_xor(acc[i], 8, 64);
        acc[i] += __shfl_xor(acc[i], 16, 64);
        acc[i] += __shfl_xor(acc[i], 32, 64);
    }
    const float dv = dinv[wid];
    const int o = wid * HID + fl * 8;
    uint4 qs = *reinterpret_cast<const uint4*>(&gin[o]);
    float s[8];
    up2(s[0], s[1], qs.x); up2(s[2], s[3], qs.y);
    up2(s[4], s[5], qs.z); up2(s[6], s[7], qs.w);
    float h[8];
#pragma unroll
    for (int i = 0; i < 8; ++i) h[i] = dv * (acc[i] + s[i]);
    if (grp != 0) return;
    if (STEP < 2) {
        uint4 gq;
        gq.x = pk2(dv * h[0], dv * h[1]); gq.y = pk2(dv * h[2], dv * h[3]);
        gq.z = pk2(dv * h[4], dv * h[5]); gq.w = pk2(dv * h[6], dv * h[7]);
        *reinterpret_cast<uint4*>(&gout[o]) = gq;
    }
    if (STEP == 0) {
        float4 x0 = *reinterpret_cast<const float4*>(&x[o]);
        float4 x1 = *reinterpret_cast<const float4*>(&x[o + 4]);
        float4 o0, o1;
        o0.x = ALPHA * x0.x + COEF * h[0]; o0.y = ALPHA * x0.y + COEF * h[1];
        o0.z = ALPHA * x0.z + COEF * h[2]; o0.w = ALPHA * x0.w + COEF * h[3];
        o1.x = ALPHA * x1.x + COEF * h[4]; o1.y = ALPHA * x1.y + COEF * h[5];
        o1.z = ALPHA * x1.z + COEF * h[6]; o1.w = ALPHA * x1.w + COEF * h[7];
        *reinterpret_cast<float4*>(&out[o])     = o0;
        *reinterpret_cast<float4*>(&out[o + 4]) = o1;
    } else if (STEP == 1) {
        float4 o0 = *reinterpret_cast<const float4*>(&out[o]);
        float4 o1 = *reinterpret_cast<const float4*>(&out[o + 4]);
        o0.x += COEF * h[0]; o0.y += COEF * h[1]; o0.z += COEF * h[2]; o0.w += COEF * h[3];
        o1.x += COEF * h[4]; o1.y += COEF * h[5]; o1.z += COEF * h[6]; o1.w += COEF * h[7];
        *reinterpret_cast<float4*>(&out[o])     = o0;
        *reinterpret_cast<float4*>(&out[o + 4]) = o1;
    } else {
        float4 o0 = *reinterpret_cast<const float4*>(&out[o]);
        float4 o1 = *reinterpret_cast<const float4*>(&out[o + 4]);
        uint4 r;
        r.x = pk2(fmaxf(o0.x + COEF * h[0], 0.f), fmaxf(o0.y + COEF * h[1], 0.f));
        r.y = pk2(fmaxf(o0.z + COEF * h[2], 0.f), fmaxf(o0.w + COEF * h[3], 0.f));
        r.z = pk2(fmaxf(o1.x + COEF * h[4], 0.f), fmaxf(o1.y + COEF * h[5], 0.f));
        r.w = pk2(fmaxf(o1.z + COEF * h[6], 0.f), fmaxf(o1.w + COEF * h[7], 0.f));
        *reinterpret_cast<uint4*>(&routb[o]) = r;
    }
}

// ---------------- SimpleConv(mean) of relu(out) + residual + relu ----------------
__global__ void final_kernel(const unsigned short* __restrict__ routb,
                             const float* __restrict__ x,
                             const int* __restrict__ rowptr, const int* __restrict__ csr,
                             float* __restrict__ res) {
    const int wid = (blockIdx.x * blockDim.x + threadIdx.x) >> 6;
    if (wid >= NN) return;
    const int lane = threadIdx.x & 63;
    const int grp = lane >> 3;
    const int fl  = lane & 7;
    const int beg = rowptr[wid], endp = rowptr[wid + 1];
    float acc[8];
#pragma unroll
    for (int i = 0; i < 8; ++i) acc[i] = 0.f;
    int e = beg + grp;
    for (; e + 8 < endp; e += 16) {
        int s0 = csr[e], s1 = csr[e + 8];
        uint4 q0 = *reinterpret_cast<const uint4*>(&routb[s0 * HID + fl * 8]);
        uint4 q1 = *reinterpret_cast<const uint4*>(&routb[s1 * HID + fl * 8]);
        acc2(acc[0], acc[1], q0.x); acc2(acc[2], acc[3], q0.y);
        acc2(acc[4], acc[5], q0.z); acc2(acc[6], acc[7], q0.w);
        acc2(acc[0], acc[1], q1.x); acc2(acc[2], acc[3], q1.y);
        acc2(acc[4], acc[5], q1.z); acc2(acc[6], acc[7], q1.w);
    }
    if (e < endp) {
        int s0 = csr[e];
        uint4 q0 = *reinterpret_cast<const uint4*>(&routb[s0 * HID + fl * 8]);
        acc2(acc[0], acc[1], q0.x); acc2(acc[2], acc[3], q0.y);
        acc2(acc[4], acc[5], q0.z); acc2(acc[6], acc[7], q0.w);
    }
#pragma unroll
    for (int i = 0; i < 8; ++i) {
        acc[i] += __shfl_xor(acc[i], 8, 64);
        acc[i] += __shfl_xor(acc[i], 16, 64);
        acc[i] += __shfl_xor(acc[i], 32, 64);
    }
    if (grp != 0) return;
    const float inv = 1.f / fmaxf((float)(endp - beg), 1.f);
    const int o = wid * HID + fl * 8;
    float4 x0 = *reinterpret_cast<const float4*>(&x[o]);
    float4 x1 = *reinterpret_cast<const float4*>(&x[o + 4]);
    float4 r0, r1;
    r0.x = fmaxf(acc[0] * inv + x0.x, 0.f); r0.y = fmaxf(acc[1] * inv + x0.y, 0.f);
    r0.z = fmaxf(acc[2] * inv + x0.z, 0.f); r0.w = fmaxf(acc[3] * inv + x0.w, 0.f);
    r1.x = fmaxf(acc[4] * inv + x1.x, 0.f); r1.y = fmaxf(acc[5] * inv + x1.y, 0.f);
    r1.z = fmaxf(acc[6] * inv + x1.z, 0.f); r1.w = fmaxf(acc[7] * inv + x1.w, 0.f);
    *reinterpret_cast<float4*>(&res[o])     = r0;
    *reinterpret_cast<float4*>(&res[o + 4]) = r1;
}

extern "C" void kernel_launch(void* const* d_in, const int* in_sizes, int n_in,
                              void* d_out, int out_size, void* d_ws, size_t ws_size,
                              hipStream_t stream) {
    const float* x  = (const float*)d_in[0];
    const int* ei   = (const int*)d_in[1];      // (2, NE): [src | dst]
    const int* srcp = ei;
    const int* dstp = ei + NE;
    float* resp     = (float*)d_out;

    size_t off = 0;
    auto carve = [&](size_t bytes) { size_t p = off; off = (off + bytes + 255) & ~(size_t)255; return p; };
    char* ws = (char*)d_ws;
    int*          hist   = (int*)          (ws + carve((size_t)NBK * SBLK * 4));
    unsigned int* buck   = (unsigned int*) (ws + carve((size_t)NE * 4));
    int*          rowptr = (int*)          (ws + carve((size_t)(NN + 1) * 4));
    float*        dinv   = (float*)        (ws + carve((size_t)NN * 4));
    int*          csr    = (int*)          (ws + carve((size_t)NE * 4));
    unsigned short* gA    = (unsigned short*)(ws + carve((size_t)NN * HID * 2));
    unsigned short* gB    = (unsigned short*)(ws + carve((size_t)NN * HID * 2));
    unsigned short* routb = (unsigned short*)(ws + carve((size_t)NN * HID * 2));
    float*        outb   = (float*)        (ws + carve((size_t)NN * HID * 4));
    (void)ws_size; (void)n_in; (void)in_sizes; (void)out_size;

    histA_kernel<<<SBLK, 256, 0, stream>>>(dstp, hist);
    scanH_kernel<<<1, 1024, 0, stream>>>(hist);
    scatterB_kernel<<<SBLK, 256, 0, stream>>>(srcp, dstp, hist, buck);
    bucketC_kernel<<<NBK, 512, 0, stream>>>(buck, hist, rowptr, dinv, csr);
    g0_kernel<<<(NN * HID / 4 + 255) / 256, 256, 0, stream>>>(x, dinv, gA);

    const int nblk = 256;                            // 4 nodes/block (1 wave each)
    const int ngrid = (NN + 3) / 4;                  // 25000
    prop_kernel<0><<<ngrid, nblk, 0, stream>>>(gA, gB, outb, x, dinv, rowptr, csr, nullptr);
    prop_kernel<1><<<ngrid, nblk, 0, stream>>>(gB, gA, outb, x, dinv, rowptr, csr, nullptr);
    prop_kernel<2><<<ngrid, nblk, 0, stream>>>(gA, nullptr, outb, x, dinv, rowptr, csr, routb);
    final_kernel<<<ngrid, nblk, 0, stream>>>(routb, x, rowptr, csr, resp);
}